// Round 2
// baseline (375.370 us; speedup 1.0000x reference)
//
#include <hip/hip_runtime.h>

#define S 48
#define T 16
#define NTOT (2 * S * S * S * T) // 3,538,944
#define NV4  (NTOT / 4)          // 884,736 vec4 work items
#define NBLK (NV4 / 256)         // 3456 blocks, exact

using f4 = __attribute__((ext_vector_type(4))) float;

__device__ __forceinline__ f4 ld4(const float* __restrict__ p) {
    return *reinterpret_cast<const f4*>(p); // all call sites are 16B-aligned
}

// ---- torch.gradient first derivative along a SPATIAL axis, vec4 over t ----
__device__ __forceinline__ f4 d1v(const float* __restrict__ fc, int i, int N, int stride) {
    const int dl = (i > 0) ? -stride : 0;
    const int dr = (i < N - 1) ? stride : 0;
    const float w = (i > 0 && i < N - 1) ? 0.5f : 1.0f;
    return (ld4(fc + dr) - ld4(fc + dl)) * w;
}

// ---- composed gradient-of-gradient along a SPATIAL axis, vec4 over t ----
//  i==0   : 0.5 f0 - f1 + 0.5 f2
//  i==1   : 0.5 f0 - 0.75 f1 + 0.25 f3
//  inner  : 0.25 (f[i-2] - 2 f[i] + f[i+2])
//  i==N-2 : 0.25 f[N-4] - 0.75 f[N-2] + 0.5 f[N-1]
//  i==N-1 : 0.5 f[N-3] - f[N-2] + 0.5 f[N-1]
__device__ __forceinline__ f4 d2cv(const float* __restrict__ fc, int i, int N, int stride) {
    int j0, j1, j2;
    float c0, c1, c2;
    if (i == 0)          { j0 = 0;  j1 = 1;  j2 = 2; c0 = 0.5f;  c1 = -1.0f;  c2 = 0.5f;  }
    else if (i == 1)     { j0 = -1; j1 = 0;  j2 = 2; c0 = 0.5f;  c1 = -0.75f; c2 = 0.25f; }
    else if (i == N - 1) { j0 = -2; j1 = -1; j2 = 0; c0 = 0.5f;  c1 = -1.0f;  c2 = 0.5f;  }
    else if (i == N - 2) { j0 = -2; j1 = 0;  j2 = 1; c0 = 0.25f; c1 = -0.75f; c2 = 0.5f;  }
    else                 { j0 = -2; j1 = 0;  j2 = 2; c0 = 0.25f; c1 = -0.5f;  c2 = 0.25f; }
    return c0 * ld4(fc + j0 * stride) + c1 * ld4(fc + j1 * stride) + c2 * ld4(fc + j2 * stride);
}

// ---- temporal derivative of the 4-pack [t0 .. t0+3], t-stride 1, T=16 ----
__device__ __forceinline__ f4 dtv(const float* __restrict__ fc, f4 c, int t0) {
    const float left  = (t0 > 0)     ? fc[-1] : 0.f;
    const float right = (t0 < T - 4) ? fc[4]  : 0.f;
    f4 r;
    r[0] = (t0 == 0)     ? (c[1] - c[0]) : 0.5f * (c[1] - left);
    r[1] = 0.5f * (c[2] - c[0]);
    r[2] = 0.5f * (c[3] - c[1]);
    r[3] = (t0 == T - 4) ? (c[3] - c[2]) : 0.5f * (right - c[2]);
    return r;
}

// Element strides:
//   V/F (B,S,S,S,3,T): z: 48, x: 2304, y: 110592; channel: 16 (ch0=Vy, ch1=Vx, ch2=Vz)
//   P/Y/X/X1/C (B,S,S,S,T): z: 16, x: 768, y: 36864
__global__ __launch_bounds__(256) void fused_loss(
    const float* __restrict__ Cmat, const float* __restrict__ V,
    const float* __restrict__ P, const float* __restrict__ Xa,
    const float* __restrict__ X1a, const float* __restrict__ F,
    const float* __restrict__ Rep, const float* __restrict__ Xlast,
    const float* __restrict__ Y, float* __restrict__ ws)
{
    const float re = Rep[0];

    const int idx = blockIdx.x * 256 + threadIdx.x;   // exact: NBLK*256 == NV4
    const int t0  = (idx & 3) * 4;                    // t-pack start: 0,4,8,12
    const int sp  = idx >> 2;                         // spatial ((b*S+y)*S+x)*S+z
    const int z   = sp % S;
    const int r1  = sp / S;
    const int x   = r1 % S;
    const int y   = (r1 / S) % S;

    const int n4    = sp * T + t0;    // offset into (B,S,S,S,T) arrays
    const int vbase = sp * 48 + t0;   // offset into (B,S,S,S,3,T) arrays

    // ---- main1 / main2 / time-loss elementwise parts ----
    const f4 yv  = ld4(Y + n4);
    const f4 dm1 = ld4(X1a + n4) - yv;
    const f4 dm2 = ld4(Xa + n4) - yv;
    f4 yp;
    yp[0] = (t0 == 0) ? Xlast[sp] : Y[n4 - 1];
    yp[1] = yv[0]; yp[2] = yv[1]; yp[3] = yv[2];
    const f4 dt1 = yp - yv;
    const f4 dt2 = ld4(Cmat + n4) - yv;

    f4 am1 = dm1 * dm1;
    f4 am2 = dm2 * dm2;
    f4 at1 = dt1 * dt1;
    f4 at2 = dt2 * dt2;

    // ---- physics loss ----
    const float* Pc = P + n4;
    const f4 dPdz = d1v(Pc, z, S, 16);
    const f4 dPdx = d1v(Pc, x, S, 768);
    const f4 dPdy = d1v(Pc, y, S, 36864);

    const float* Vyc = V + vbase;        // channel 0 = Vy
    const float* Vxc = V + vbase + 16;   // channel 1 = Vx
    const float* Vzc = V + vbase + 32;   // channel 2 = Vz
    const f4 cy = ld4(Vyc), cx = ld4(Vxc), cz = ld4(Vzc);

    f4 aphy;
    f4 div;

    // channel Vy -> e1 (dPdy, Fy); contributes dVydy to divergence
    {
        const f4 ddt = dtv(Vyc, cy, t0);
        const f4 ddz = d1v(Vyc, z, S, 48);
        const f4 ddx = d1v(Vyc, x, S, 2304);
        const f4 ddy = d1v(Vyc, y, S, 110592);
        const f4 lap = d2cv(Vyc, z, S, 48) + d2cv(Vyc, x, S, 2304) + d2cv(Vyc, y, S, 110592);
        const f4 e1  = ddt + (cx * ddx + cy * ddy + cz * ddz + dPdy) - re * lap + ld4(F + vbase);
        aphy = e1 * e1;
        div  = ddy;
    }
    // channel Vx -> e2 (dPdx, Fx); contributes dVxdx
    {
        const f4 ddt = dtv(Vxc, cx, t0);
        const f4 ddz = d1v(Vxc, z, S, 48);
        const f4 ddx = d1v(Vxc, x, S, 2304);
        const f4 ddy = d1v(Vxc, y, S, 110592);
        const f4 lap = d2cv(Vxc, z, S, 48) + d2cv(Vxc, x, S, 2304) + d2cv(Vxc, y, S, 110592);
        const f4 e2  = ddt + (cx * ddx + cy * ddy + cz * ddz + dPdx) - re * lap + ld4(F + vbase + 16);
        aphy += e2 * e2;
        div  += ddx;
    }
    // channel Vz -> e3 (dPdz, Fz); contributes dVzdz
    {
        const f4 ddt = dtv(Vzc, cz, t0);
        const f4 ddz = d1v(Vzc, z, S, 48);
        const f4 ddx = d1v(Vzc, x, S, 2304);
        const f4 ddy = d1v(Vzc, y, S, 110592);
        const f4 lap = d2cv(Vzc, z, S, 48) + d2cv(Vzc, x, S, 2304) + d2cv(Vzc, y, S, 110592);
        const f4 e3  = ddt + (cx * ddx + cy * ddy + cz * ddz + dPdz) - re * lap + ld4(F + vbase + 32);
        aphy += e3 * e3;
        div  += ddz;       // e4 = dVxdx + dVydy + dVzdz  (this term was missing in R1)
        aphy += div * div;
    }

    // ---- horizontal sums of the vec4 accumulators ----
    float sm1 = am1[0] + am1[1] + am1[2] + am1[3];
    float sm2 = am2[0] + am2[1] + am2[2] + am2[3];
    float sph = aphy[0] + aphy[1] + aphy[2] + aphy[3];
    float st1 = at1[0] + at1[1] + at1[2] + at1[3];
    float st2 = at2[0] + at2[1] + at2[2] + at2[3];

    // ---- reduction: wave shuffle -> LDS -> 5 atomics per block ----
    #pragma unroll
    for (int off = 32; off > 0; off >>= 1) {
        sm1 += __shfl_down(sm1, off);
        sm2 += __shfl_down(sm2, off);
        sph += __shfl_down(sph, off);
        st1 += __shfl_down(st1, off);
        st2 += __shfl_down(st2, off);
    }
    __shared__ float sred[4][5];
    const int lane = threadIdx.x & 63;
    const int wv   = threadIdx.x >> 6;
    if (lane == 0) {
        sred[wv][0] = sm1; sred[wv][1] = sm2; sred[wv][2] = sph;
        sred[wv][3] = st1; sred[wv][4] = st2;
    }
    __syncthreads();
    if (threadIdx.x == 0) {
        float s0 = 0.f, s1 = 0.f, s2 = 0.f, s3 = 0.f, s4 = 0.f;
        #pragma unroll
        for (int w = 0; w < 4; ++w) {
            s0 += sred[w][0]; s1 += sred[w][1]; s2 += sred[w][2];
            s3 += sred[w][3]; s4 += sred[w][4];
        }
        atomicAdd(&ws[0], s0);
        atomicAdd(&ws[1], s1);
        atomicAdd(&ws[2], s2);
        atomicAdd(&ws[3], s3);
        atomicAdd(&ws[4], s4);
    }
}

__global__ void finalize_kernel(const float* __restrict__ ws, float* __restrict__ out) {
    const float invN = 1.0f / (float)NTOT;
    const float m1  = ws[0] * invN;
    const float m2  = ws[1] * invN;
    const float phy = ws[2] * invN;
    const float t1  = ws[3] * invN;
    const float t2  = ws[4] * invN;
    out[0] = m1;
    out[1] = m2;
    out[2] = phy;
    out[3] = (t1 < t2) ? (t2 - t1) : 0.0f;
}

extern "C" void kernel_launch(void* const* d_in, const int* in_sizes, int n_in,
                              void* d_out, int out_size, void* d_ws, size_t ws_size,
                              hipStream_t stream) {
    // setup_inputs order:
    // 0 C_all, 1 V_all, 2 P_all, 3 X_all, 4 X1_all, 5 F_all, 6 Re, 7 X_last,
    // 8 Y_data, 9 maskd0, 10 maskd1, 11 maskd2
    const float* Cmat  = (const float*)d_in[0];
    const float* V     = (const float*)d_in[1];
    const float* P     = (const float*)d_in[2];
    const float* Xa    = (const float*)d_in[3];
    const float* X1a   = (const float*)d_in[4];
    const float* F     = (const float*)d_in[5];
    const float* Rep   = (const float*)d_in[6];
    const float* Xlast = (const float*)d_in[7];
    const float* Y     = (const float*)d_in[8];

    float* ws  = (float*)d_ws;
    float* out = (float*)d_out;

    hipMemsetAsync(ws, 0, 5 * sizeof(float), stream);
    fused_loss<<<NBLK, 256, 0, stream>>>(Cmat, V, P, Xa, X1a, F, Rep, Xlast, Y, ws);
    finalize_kernel<<<1, 1, 0, stream>>>(ws, out);
}